// Round 2
// baseline (1407.635 us; speedup 1.0000x reference)
//
#include <hip/hip_runtime.h>

typedef unsigned short u16;
typedef __attribute__((ext_vector_type(8))) unsigned short u16x8;

#define NAG 8      // agents per episode
#define FIN 64
#define DDIM 64
#define NHEAD 4
#define HD 256     // H*D
#define MDIM 64
#define NACT 10
#define EPG 56     // edges per group = 8*7
#define NTOT 32768 // B*A

__device__ __forceinline__ float b2f(u16 u) {
  return __uint_as_float(((unsigned int)u) << 16);
}
__device__ __forceinline__ u16 f2b(float f) {
  unsigned int x = __float_as_uint(f);
  unsigned int r = x + 0x7fffu + ((x >> 16) & 1u);   // RNE; values finite
  return (u16)(r >> 16);
}

// dual-dtype staging: dst (LDS float*) <- src element i (f32 or bf16)
#define STAGE_LOOP(dst, srcf, srcb, n)                                       \
  do {                                                                       \
    if (use_f32) {                                                           \
      for (int i = t; i < (n); i += 256) (dst)[i] = (srcf)[i];               \
    } else {                                                                 \
      for (int i = t; i < (n); i += 256) (dst)[i] = b2f((srcb)[i]);          \
    }                                                                        \
  } while (0)

__global__ __launch_bounds__(256) void gnn_rnn_kernel(
    const void* __restrict__ x, const void* __restrict__ edge_attr,
    const void* __restrict__ hidden,
    const void* __restrict__ Wl, const void* __restrict__ bl,
    const void* __restrict__ Wr, const void* __restrict__ br,
    const void* __restrict__ We, const void* __restrict__ be,
    const void* __restrict__ att, const void* __restrict__ bias_g,
    const void* __restrict__ W_ih, const void* __restrict__ W_hh,
    const void* __restrict__ b_ih, const void* __restrict__ b_hh,
    const void* __restrict__ ln_g, const void* __restrict__ ln_b,
    const void* __restrict__ Wq, const void* __restrict__ bq,
    void* __restrict__ d_out)
{
  __shared__ __align__(16) float s_x[NAG][FIN];
  __shared__ __align__(16) float s_hid[NAG][MDIM];
  __shared__ float s_ea[EPG * 3];
  __shared__ __align__(16) float s_xl[NAG][HD];
  __shared__ __align__(16) float s_xr[NAG][HD];
  __shared__ float s_bl[HD], s_br[HD], s_be[HD], s_att[HD];
  __shared__ float s_We[HD * 3];
  __shared__ float s_bg[DDIM];
  __shared__ float s_alpha[EPG][NHEAD];
  __shared__ __align__(16) float s_hg[NAG][DDIM];
  __shared__ float s_gi[NAG][192];
  __shared__ float s_gh[NAG][192];
  __shared__ __align__(16) float s_h[NAG][MDIM];
  __shared__ __align__(16) float s_ln[NAG][MDIM];
  __shared__ float s_Wq[NACT * MDIM];
  __shared__ float s_bq[NACT];
  __shared__ float s_lng[MDIM], s_lnb[MDIM];
  __shared__ float s_bih[192], s_bhh[192];

  const int t = threadIdx.x;
  const int b = blockIdx.x;

  // ---------- Phase 0: runtime dtype sniff (uniform across lanes & blocks) ----------
  int bad = 0;
#pragma unroll
  for (int i = 0; i < 64; i++) {
    unsigned int u = ((const u16*)Wl)[i];
    unsigned int ex = (u >> 7) & 0xFFu;
    bad += (ex >= 130u) ? 1 : 0;
  }
  const bool use_f32 = (bad >= 4);

  // ---------- Phase 1: stage inputs + small weights into LDS ----------
  STAGE_LOOP((float*)s_x,  (const float*)x + b * (NAG * FIN),
                           (const u16*)x + b * (NAG * FIN), NAG * FIN);
  STAGE_LOOP((float*)s_hid,(const float*)hidden + b * (NAG * MDIM),
                           (const u16*)hidden + b * (NAG * MDIM), NAG * MDIM);
  STAGE_LOOP(s_ea, (const float*)edge_attr + b * (EPG * 3),
                   (const u16*)edge_attr + b * (EPG * 3), EPG * 3);
  STAGE_LOOP(s_bl, (const float*)bl, (const u16*)bl, HD);
  STAGE_LOOP(s_br, (const float*)br, (const u16*)br, HD);
  STAGE_LOOP(s_be, (const float*)be, (const u16*)be, HD);
  STAGE_LOOP(s_att,(const float*)att,(const u16*)att, HD);
  STAGE_LOOP(s_We, (const float*)We, (const u16*)We, HD * 3);
  STAGE_LOOP(s_bg, (const float*)bias_g, (const u16*)bias_g, DDIM);
  STAGE_LOOP(s_lng,(const float*)ln_g, (const u16*)ln_g, MDIM);
  STAGE_LOOP(s_lnb,(const float*)ln_b, (const u16*)ln_b, MDIM);
  STAGE_LOOP(s_bih,(const float*)b_ih, (const u16*)b_ih, 192);
  STAGE_LOOP(s_bhh,(const float*)b_hh, (const u16*)b_hh, 192);
  STAGE_LOOP(s_Wq, (const float*)Wq, (const u16*)Wq, NACT * MDIM);
  STAGE_LOOP(s_bq, (const float*)bq, (const u16*)bq, NACT);
  __syncthreads();

  // ---------- Phase 2: xl = x@Wl^T+bl, xr = x@Wr^T+br (col t, all 8 agents) ----------
  {
    float accl[NAG], accr[NAG];
#pragma unroll
    for (int a = 0; a < NAG; a++) { accl[a] = s_bl[t]; accr[a] = s_br[t]; }
#pragma unroll
    for (int kk = 0; kk < 8; kk++) {
      float wlf[8], wrf[8];
      if (use_f32) {
        const float4* lp = (const float4*)((const float*)Wl + t * 64 + kk * 8);
        const float4* rp = (const float4*)((const float*)Wr + t * 64 + kk * 8);
        float4 l0 = lp[0], l1 = lp[1], r0 = rp[0], r1 = rp[1];
        wlf[0]=l0.x; wlf[1]=l0.y; wlf[2]=l0.z; wlf[3]=l0.w;
        wlf[4]=l1.x; wlf[5]=l1.y; wlf[6]=l1.z; wlf[7]=l1.w;
        wrf[0]=r0.x; wrf[1]=r0.y; wrf[2]=r0.z; wrf[3]=r0.w;
        wrf[4]=r1.x; wrf[5]=r1.y; wrf[6]=r1.z; wrf[7]=r1.w;
      } else {
        u16x8 wl8 = *(const u16x8*)((const u16*)Wl + t * 64 + kk * 8);
        u16x8 wr8 = *(const u16x8*)((const u16*)Wr + t * 64 + kk * 8);
#pragma unroll
        for (int j = 0; j < 8; j++) { wlf[j] = b2f(wl8[j]); wrf[j] = b2f(wr8[j]); }
      }
#pragma unroll
      for (int a = 0; a < NAG; a++) {
        const float4* xp = (const float4*)&s_x[a][kk * 8];
        float4 x0 = xp[0], x1 = xp[1];
        accl[a] += x0.x * wlf[0] + x0.y * wlf[1] + x0.z * wlf[2] + x0.w * wlf[3]
                 + x1.x * wlf[4] + x1.y * wlf[5] + x1.z * wlf[6] + x1.w * wlf[7];
        accr[a] += x0.x * wrf[0] + x0.y * wrf[1] + x0.z * wrf[2] + x0.w * wrf[3]
                 + x1.x * wrf[4] + x1.y * wrf[5] + x1.z * wrf[6] + x1.w * wrf[7];
      }
    }
#pragma unroll
    for (int a = 0; a < NAG; a++) { s_xl[a][t] = accl[a]; s_xr[a][t] = accr[a]; }
  }
  __syncthreads();

  // ---------- Phase 3: edge logits (GATv2) ----------
  if (t < EPG * NHEAD) {
    const int e = t >> 2, h = t & 3;
    const int s = e / 7, k = e % 7;
    const int j = k + (k >= s ? 1 : 0);   // dst agent
    const float ea0 = s_ea[e * 3], ea1 = s_ea[e * 3 + 1], ea2 = s_ea[e * 3 + 2];
    const float* xls = &s_xl[s][h * 64];
    const float* xrj = &s_xr[j][h * 64];
    const float* wep = &s_We[h * 64 * 3];
    const float* bep = &s_be[h * 64];
    const float* atp = &s_att[h * 64];
    float lg = 0.f;
#pragma unroll 8
    for (int d = 0; d < 64; d++) {
      float ee = ea0 * wep[d * 3] + ea1 * wep[d * 3 + 1] + ea2 * wep[d * 3 + 2] + bep[d];
      float mv = xls[d] + xrj[d] + ee;
      mv = mv > 0.f ? mv : 0.2f * mv;
      lg += mv * atp[d];
    }
    s_alpha[e][h] = lg;
  }
  __syncthreads();

  // ---------- Phase 4: per-(dst,head) softmax over 7 in-edges ----------
  if (t < 32) {
    const int j = t >> 2, h = t & 3;
    float mx = -1e30f;
#pragma unroll
    for (int s = 0; s < 8; s++) {
      if (s == j) continue;
      int e = s * 7 + (j > s ? j - 1 : j);
      mx = fmaxf(mx, s_alpha[e][h]);
    }
    float sum = 0.f;
#pragma unroll
    for (int s = 0; s < 8; s++) {
      if (s == j) continue;
      int e = s * 7 + (j > s ? j - 1 : j);
      float ex = __expf(s_alpha[e][h] - mx);
      s_alpha[e][h] = ex;
      sum += ex;
    }
    float inv = 1.f / sum;
#pragma unroll
    for (int s = 0; s < 8; s++) {
      if (s == j) continue;
      int e = s * 7 + (j > s ? j - 1 : j);
      s_alpha[e][h] *= inv;
    }
  }
  __syncthreads();

  // ---------- Phase 5: aggregate, mean over heads, +bias, ReLU ----------
  for (int it = t; it < 512; it += 256) {
    const int jj = it >> 6, dd = it & 63;
    float acc = 0.f;
#pragma unroll
    for (int h = 0; h < 4; h++) {
#pragma unroll
      for (int s = 0; s < 8; s++) {
        if (s == jj) continue;
        int e = s * 7 + (jj > s ? jj - 1 : jj);
        acc += s_alpha[e][h] * s_xl[s][h * 64 + dd];
      }
    }
    float v = acc * 0.25f + s_bg[dd];
    s_hg[jj][dd] = v > 0.f ? v : 0.f;
  }
  __syncthreads();

  // ---------- Phase 6: GRU projections gi, gh (col t<192, all 8 agents) ----------
  if (t < 192) {
    float gia[NAG], gha[NAG];
#pragma unroll
    for (int a = 0; a < NAG; a++) { gia[a] = s_bih[t]; gha[a] = s_bhh[t]; }
#pragma unroll
    for (int kk = 0; kk < 8; kk++) {
      float wif[8], whf[8];
      if (use_f32) {
        const float4* ip = (const float4*)((const float*)W_ih + t * 64 + kk * 8);
        const float4* hp = (const float4*)((const float*)W_hh + t * 64 + kk * 8);
        float4 i0 = ip[0], i1 = ip[1], h0 = hp[0], h1 = hp[1];
        wif[0]=i0.x; wif[1]=i0.y; wif[2]=i0.z; wif[3]=i0.w;
        wif[4]=i1.x; wif[5]=i1.y; wif[6]=i1.z; wif[7]=i1.w;
        whf[0]=h0.x; whf[1]=h0.y; whf[2]=h0.z; whf[3]=h0.w;
        whf[4]=h1.x; whf[5]=h1.y; whf[6]=h1.z; whf[7]=h1.w;
      } else {
        u16x8 wi8 = *(const u16x8*)((const u16*)W_ih + t * 64 + kk * 8);
        u16x8 wh8 = *(const u16x8*)((const u16*)W_hh + t * 64 + kk * 8);
#pragma unroll
        for (int j = 0; j < 8; j++) { wif[j] = b2f(wi8[j]); whf[j] = b2f(wh8[j]); }
      }
#pragma unroll
      for (int a = 0; a < NAG; a++) {
        const float4* gp = (const float4*)&s_hg[a][kk * 8];
        const float4* hp2 = (const float4*)&s_hid[a][kk * 8];
        float4 g0 = gp[0], g1 = gp[1];
        float4 h0 = hp2[0], h1 = hp2[1];
        gia[a] += g0.x * wif[0] + g0.y * wif[1] + g0.z * wif[2] + g0.w * wif[3]
                + g1.x * wif[4] + g1.y * wif[5] + g1.z * wif[6] + g1.w * wif[7];
        gha[a] += h0.x * whf[0] + h0.y * whf[1] + h0.z * whf[2] + h0.w * whf[3]
                + h1.x * whf[4] + h1.y * whf[5] + h1.z * whf[6] + h1.w * whf[7];
      }
    }
#pragma unroll
    for (int a = 0; a < NAG; a++) { s_gi[a][t] = gia[a]; s_gh[a][t] = gha[a]; }
  }
  __syncthreads();

  // ---------- Phase 7: GRU gates + write h (output 1, offset N*NACT elems) ----------
  for (int it = t; it < 512; it += 256) {
    const int a = it >> 6, m = it & 63;
    float ir = s_gi[a][m], iz = s_gi[a][64 + m], inn = s_gi[a][128 + m];
    float hr = s_gh[a][m], hz = s_gh[a][64 + m], hn = s_gh[a][128 + m];
    float r = 1.f / (1.f + __expf(-(ir + hr)));
    float z = 1.f / (1.f + __expf(-(iz + hz)));
    float xg = inn + r * hn;
    xg = fminf(fmaxf(xg, -20.f), 20.f);
    float e2 = __expf(2.f * xg);
    float n = (e2 - 1.f) / (e2 + 1.f);
    float hv = (1.f - z) * n + z * s_hid[a][m];
    s_h[a][m] = hv;
    const int oi = NTOT * NACT + (b * NAG + a) * MDIM + m;
    if (use_f32) ((float*)d_out)[oi] = hv;
    else         ((u16*)d_out)[oi] = f2b(hv);
  }
  __syncthreads();

  // ---------- Phase 8: LayerNorm (wave w handles rows w and w+4; lane = col) ----------
  {
    const int w = t >> 6, l = t & 63;
#pragma unroll
    for (int rr = 0; rr < 2; rr++) {
      const int a = w + rr * 4;
      float v = s_h[a][l];
      float sum = v;
#pragma unroll
      for (int off = 1; off < 64; off <<= 1) sum += __shfl_xor(sum, off, 64);
      float mu = sum * (1.f / 64.f);
      float dv = v - mu;
      float s2 = dv * dv;
#pragma unroll
      for (int off = 1; off < 64; off <<= 1) s2 += __shfl_xor(s2, off, 64);
      float var = s2 * (1.f / 64.f);
      float hln = dv * rsqrtf(var + 1e-5f) * s_lng[l] + s_lnb[l];
      s_ln[a][l] = hln;
    }
  }
  __syncthreads();

  // ---------- Phase 9: q = hln @ Wq^T + bq (output 0) ----------
  if (t < NAG * NACT) {
    const int a = t / NACT, o = t % NACT;
    float acc = s_bq[o];
    const float* lp = s_ln[a];
    const float* wp = &s_Wq[o * 64];
#pragma unroll 8
    for (int m = 0; m < 64; m++) acc += lp[m] * wp[m];
    const int oi = (b * NAG + a) * NACT + o;
    if (use_f32) ((float*)d_out)[oi] = acc;
    else         ((u16*)d_out)[oi] = f2b(acc);
  }
}

extern "C" void kernel_launch(void* const* d_in, const int* in_sizes, int n_in,
                              void* d_out, int out_size, void* d_ws, size_t ws_size,
                              hipStream_t stream) {
  const int N  = in_sizes[0] / FIN;   // 32768
  const int Bn = N / NAG;             // 4096 episodes
  gnn_rnn_kernel<<<Bn, 256, 0, stream>>>(
      d_in[0], d_in[1], d_in[2],               // x, edge_attr, hidden (d_in[3]=edge_index unused)
      d_in[4], d_in[5], d_in[6], d_in[7],      // Wl, bl, Wr, br
      d_in[8], d_in[9], d_in[10], d_in[11],    // We, be, att, bias_g
      d_in[12], d_in[13], d_in[14], d_in[15],  // W_ih, W_hh, b_ih, b_hh
      d_in[16], d_in[17], d_in[18], d_in[19],  // ln_g, ln_b, Wq, bq
      d_out);
}

// Round 3
// 294.478 us; speedup vs baseline: 4.7801x; 4.7801x over previous
//
#include <hip/hip_runtime.h>

#define NAG 8      // agents per episode
#define FIN 64
#define DDIM 64
#define NHEAD 4
#define HD 256     // H*D
#define HDP 257    // padded row for s_xl/s_xr (bank spread)
#define MDIM 64
#define NACT 10
#define EPG 56     // edges per group = 8*7
#define NTOT 32768 // B*A

__global__ __launch_bounds__(256) void gnn_rnn_kernel(
    const float* __restrict__ x, const float* __restrict__ edge_attr,
    const float* __restrict__ hidden,
    const float* __restrict__ Wl, const float* __restrict__ bl,
    const float* __restrict__ Wr, const float* __restrict__ br,
    const float* __restrict__ We, const float* __restrict__ be,
    const float* __restrict__ att, const float* __restrict__ bias_g,
    const float* __restrict__ W_ih, const float* __restrict__ W_hh,
    const float* __restrict__ b_ih, const float* __restrict__ b_hh,
    const float* __restrict__ ln_g, const float* __restrict__ ln_b,
    const float* __restrict__ Wq, const float* __restrict__ bq,
    float* __restrict__ d_out)
{
  __shared__ __align__(16) float s_x[NAG][FIN];
  __shared__ __align__(16) float s_hid[NAG][MDIM];
  __shared__ float s_ea[EPG * 3];
  __shared__ float s_xl[NAG][HDP];
  __shared__ float s_xr[NAG][HDP];
  __shared__ float s_bl[HD], s_br[HD], s_be[HD], s_att[HD];
  __shared__ float s_We[HD * 3];
  __shared__ float s_bg[DDIM];
  __shared__ float s_alpha[EPG][NHEAD];
  __shared__ __align__(16) float s_hg[NAG][DDIM];
  __shared__ float s_gi[NAG][192];
  __shared__ float s_gh[NAG][192];
  __shared__ __align__(16) float s_h[NAG][MDIM];
  __shared__ __align__(16) float s_ln[NAG][MDIM];
  __shared__ float s_Wq[NACT * MDIM];
  __shared__ float s_bq[NACT];
  __shared__ float s_lng[MDIM], s_lnb[MDIM];
  __shared__ float s_bih[192], s_bhh[192];

  const int t = threadIdx.x;
  const int b = blockIdx.x;

  // ---------- Phase 1: stage inputs + small weights into LDS ----------
  {
    const float* xb = x + b * (NAG * FIN);
    ((float*)s_x)[t]       = xb[t];
    ((float*)s_x)[t + 256] = xb[t + 256];
    const float* hb = hidden + b * (NAG * MDIM);
    ((float*)s_hid)[t]       = hb[t];
    ((float*)s_hid)[t + 256] = hb[t + 256];
    const float* eb = edge_attr + b * (EPG * 3);
    if (t < EPG * 3) s_ea[t] = eb[t];
    s_bl[t] = bl[t];  s_br[t] = br[t];
    s_be[t] = be[t];  s_att[t] = att[t];
    s_We[t] = We[t]; s_We[t + 256] = We[t + 256]; s_We[t + 512] = We[t + 512];
    if (t < DDIM) { s_bg[t] = bias_g[t]; s_lng[t] = ln_g[t]; s_lnb[t] = ln_b[t]; }
    if (t < 192)  { s_bih[t] = b_ih[t]; s_bhh[t] = b_hh[t]; }
    s_Wq[t] = Wq[t]; s_Wq[t + 256] = Wq[t + 256];
    if (t < 128) s_Wq[t + 512] = Wq[t + 512];
    if (t < NACT) s_bq[t] = bq[t];
  }
  __syncthreads();

  // ---------- Phase 2: xl = x@Wl^T+bl, xr = x@Wr^T+br (col t, all 8 agents) ----------
  {
    float accl[NAG], accr[NAG];
#pragma unroll
    for (int a = 0; a < NAG; a++) { accl[a] = s_bl[t]; accr[a] = s_br[t]; }
#pragma unroll
    for (int kk = 0; kk < 8; kk++) {
      const float4* lp = (const float4*)(Wl + t * 64 + kk * 8);
      const float4* rp = (const float4*)(Wr + t * 64 + kk * 8);
      float4 l0 = lp[0], l1 = lp[1], r0 = rp[0], r1 = rp[1];
#pragma unroll
      for (int a = 0; a < NAG; a++) {
        const float4* xp = (const float4*)&s_x[a][kk * 8];
        float4 x0 = xp[0], x1 = xp[1];
        accl[a] += x0.x * l0.x + x0.y * l0.y + x0.z * l0.z + x0.w * l0.w
                 + x1.x * l1.x + x1.y * l1.y + x1.z * l1.z + x1.w * l1.w;
        accr[a] += x0.x * r0.x + x0.y * r0.y + x0.z * r0.z + x0.w * r0.w
                 + x1.x * r1.x + x1.y * r1.y + x1.z * r1.z + x1.w * r1.w;
      }
    }
#pragma unroll
    for (int a = 0; a < NAG; a++) { s_xl[a][t] = accl[a]; s_xr[a][t] = accr[a]; }
  }
  __syncthreads();

  // ---------- Phase 3: edge logits (GATv2) ----------
  if (t < EPG * NHEAD) {
    const int e = t >> 2, h = t & 3;
    const int s = e / 7, k = e % 7;
    const int j = k + (k >= s ? 1 : 0);   // dst agent
    const float ea0 = s_ea[e * 3], ea1 = s_ea[e * 3 + 1], ea2 = s_ea[e * 3 + 2];
    const float* xls = &s_xl[s][h * 64];
    const float* xrj = &s_xr[j][h * 64];
    const float* wep = &s_We[h * 64 * 3];
    const float* bep = &s_be[h * 64];
    const float* atp = &s_att[h * 64];
    float lg = 0.f;
#pragma unroll 8
    for (int d = 0; d < 64; d++) {
      float ee = ea0 * wep[d * 3] + ea1 * wep[d * 3 + 1] + ea2 * wep[d * 3 + 2] + bep[d];
      float mv = xls[d] + xrj[d] + ee;
      mv = mv > 0.f ? mv : 0.2f * mv;
      lg += mv * atp[d];
    }
    s_alpha[e][h] = lg;
  }
  __syncthreads();

  // ---------- Phase 4: per-(dst,head) softmax over 7 in-edges ----------
  if (t < 32) {
    const int j = t >> 2, h = t & 3;
    float mx = -1e30f;
#pragma unroll
    for (int s = 0; s < 8; s++) {
      if (s == j) continue;
      int e = s * 7 + (j > s ? j - 1 : j);
      mx = fmaxf(mx, s_alpha[e][h]);
    }
    float sum = 0.f;
#pragma unroll
    for (int s = 0; s < 8; s++) {
      if (s == j) continue;
      int e = s * 7 + (j > s ? j - 1 : j);
      float ex = __expf(s_alpha[e][h] - mx);
      s_alpha[e][h] = ex;
      sum += ex;
    }
    float inv = 1.f / sum;
#pragma unroll
    for (int s = 0; s < 8; s++) {
      if (s == j) continue;
      int e = s * 7 + (j > s ? j - 1 : j);
      s_alpha[e][h] *= inv;
    }
  }
  __syncthreads();

  // ---------- Phase 5: aggregate, mean over heads, +bias, ReLU ----------
  for (int it = t; it < 512; it += 256) {
    const int jj = it >> 6, dd = it & 63;
    float acc = 0.f;
#pragma unroll
    for (int h = 0; h < 4; h++) {
#pragma unroll
      for (int s = 0; s < 8; s++) {
        if (s == jj) continue;
        int e = s * 7 + (jj > s ? jj - 1 : jj);
        acc += s_alpha[e][h] * s_xl[s][h * 64 + dd];
      }
    }
    float v = acc * 0.25f + s_bg[dd];
    s_hg[jj][dd] = v > 0.f ? v : 0.f;
  }
  __syncthreads();

  // ---------- Phase 6: GRU projections gi, gh (col t<192, all 8 agents) ----------
  if (t < 192) {
    float gia[NAG], gha[NAG];
#pragma unroll
    for (int a = 0; a < NAG; a++) { gia[a] = s_bih[t]; gha[a] = s_bhh[t]; }
#pragma unroll
    for (int kk = 0; kk < 8; kk++) {
      const float4* ip = (const float4*)(W_ih + t * 64 + kk * 8);
      const float4* hp = (const float4*)(W_hh + t * 64 + kk * 8);
      float4 i0 = ip[0], i1 = ip[1], w0 = hp[0], w1 = hp[1];
#pragma unroll
      for (int a = 0; a < NAG; a++) {
        const float4* gp = (const float4*)&s_hg[a][kk * 8];
        const float4* hp2 = (const float4*)&s_hid[a][kk * 8];
        float4 g0 = gp[0], g1 = gp[1];
        float4 h0 = hp2[0], h1 = hp2[1];
        gia[a] += g0.x * i0.x + g0.y * i0.y + g0.z * i0.z + g0.w * i0.w
                + g1.x * i1.x + g1.y * i1.y + g1.z * i1.z + g1.w * i1.w;
        gha[a] += h0.x * w0.x + h0.y * w0.y + h0.z * w0.z + h0.w * w0.w
                + h1.x * w1.x + h1.y * w1.y + h1.z * w1.z + h1.w * w1.w;
      }
    }
#pragma unroll
    for (int a = 0; a < NAG; a++) { s_gi[a][t] = gia[a]; s_gh[a][t] = gha[a]; }
  }
  __syncthreads();

  // ---------- Phase 7: GRU gates + write h (output 1, offset N*NACT elems) ----------
  for (int it = t; it < 512; it += 256) {
    const int a = it >> 6, m = it & 63;
    float ir = s_gi[a][m], iz = s_gi[a][64 + m], inn = s_gi[a][128 + m];
    float hr = s_gh[a][m], hz = s_gh[a][64 + m], hn = s_gh[a][128 + m];
    float r = 1.f / (1.f + __expf(-(ir + hr)));
    float z = 1.f / (1.f + __expf(-(iz + hz)));
    float xg = inn + r * hn;
    xg = fminf(fmaxf(xg, -20.f), 20.f);
    float e2 = __expf(2.f * xg);
    float n = (e2 - 1.f) / (e2 + 1.f);
    float hv = (1.f - z) * n + z * s_hid[a][m];
    s_h[a][m] = hv;
    d_out[NTOT * NACT + (b * NAG + a) * MDIM + m] = hv;
  }
  __syncthreads();

  // ---------- Phase 8: LayerNorm (wave w handles rows w and w+4; lane = col) ----------
  {
    const int w = t >> 6, l = t & 63;
#pragma unroll
    for (int rr = 0; rr < 2; rr++) {
      const int a = w + rr * 4;
      float v = s_h[a][l];
      float sum = v;
#pragma unroll
      for (int off = 1; off < 64; off <<= 1) sum += __shfl_xor(sum, off, 64);
      float mu = sum * (1.f / 64.f);
      float dv = v - mu;
      float s2 = dv * dv;
#pragma unroll
      for (int off = 1; off < 64; off <<= 1) s2 += __shfl_xor(s2, off, 64);
      float var = s2 * (1.f / 64.f);
      float hln = dv * rsqrtf(var + 1e-5f) * s_lng[l] + s_lnb[l];
      s_ln[a][l] = hln;
    }
  }
  __syncthreads();

  // ---------- Phase 9: q = hln @ Wq^T + bq (output 0) ----------
  if (t < NAG * NACT) {
    const int a = t / NACT, o = t % NACT;
    float acc = s_bq[o];
    const float* lp = s_ln[a];
    const float* wp = &s_Wq[o * 64];
#pragma unroll 8
    for (int m = 0; m < 64; m++) acc += lp[m] * wp[m];
    d_out[(b * NAG + a) * NACT + o] = acc;
  }
}

extern "C" void kernel_launch(void* const* d_in, const int* in_sizes, int n_in,
                              void* d_out, int out_size, void* d_ws, size_t ws_size,
                              hipStream_t stream) {
  const int N  = in_sizes[0] / FIN;   // 32768
  const int Bn = N / NAG;             // 4096 episodes
  gnn_rnn_kernel<<<Bn, 256, 0, stream>>>(
      (const float*)d_in[0], (const float*)d_in[1], (const float*)d_in[2],
      (const float*)d_in[4], (const float*)d_in[5], (const float*)d_in[6],
      (const float*)d_in[7], (const float*)d_in[8], (const float*)d_in[9],
      (const float*)d_in[10], (const float*)d_in[11], (const float*)d_in[12],
      (const float*)d_in[13], (const float*)d_in[14], (const float*)d_in[15],
      (const float*)d_in[16], (const float*)d_in[17], (const float*)d_in[18],
      (const float*)d_in[19], (float*)d_out);
}

// Round 4
// 203.285 us; speedup vs baseline: 6.9244x; 1.4486x over previous
//
#include <hip/hip_runtime.h>

typedef unsigned short u16;
typedef __attribute__((ext_vector_type(8))) short bf16x8;
typedef __attribute__((ext_vector_type(4))) float f32x4;

#define NAG 8      // agents per episode
#define FIN 64
#define DDIM 64
#define NHEAD 4
#define HD 256     // H*D
#define HDP 257    // padded row for s_xl/s_xr
#define MDIM 64
#define NACT 10
#define EPG 56     // edges per group = 8*7
#define NTOT 32768 // B*A
#define ABP 72     // padded bf16 A-row (144 B = 9*16B, bank-spread, 16B-aligned)

__device__ __forceinline__ u16 f2b(float f) {
  unsigned int x = __float_as_uint(f);
  unsigned int r = x + 0x7fffu + ((x >> 16) & 1u);   // RNE; values finite
  return (u16)(r >> 16);
}

// ---------- pre-kernel: repack Wl/Wr/W_ih/W_hh into bf16 B-fragment order ----------
// wsB[T][ks][lane][8]: T 0-15 = Wl col-tiles, 16-31 = Wr, 32-43 = W_ih, 44-55 = W_hh.
// Fragment: lane L holds B[k = ks*32 + (L>>4)*8 + j][n = ntile*16 + (L&15)], i.e.
// source W[row = ntile*16 + (L&15)][k] for the row-major [n][64] weight.
__global__ __launch_bounds__(256) void prep_weights(
    const float* __restrict__ Wl, const float* __restrict__ Wr,
    const float* __restrict__ Wih, const float* __restrict__ Whh,
    u16* __restrict__ wsB)
{
  const int idx = blockIdx.x * 256 + threadIdx.x;   // 0 .. 56*2*64-1
  if (idx >= 56 * 2 * 64) return;
  const int L  = idx & 63;
  const int ks = (idx >> 6) & 1;
  const int T  = idx >> 7;
  const float* W; int row0;
  if      (T < 16) { W = Wl;  row0 = T * 16; }
  else if (T < 32) { W = Wr;  row0 = (T - 16) * 16; }
  else if (T < 44) { W = Wih; row0 = (T - 32) * 16; }
  else             { W = Whh; row0 = (T - 44) * 16; }
  const int row = row0 + (L & 15);
  const int k0  = ks * 32 + (L >> 4) * 8;
  u16 v[8];
#pragma unroll
  for (int j = 0; j < 8; j++) v[j] = f2b(W[row * 64 + k0 + j]);
  *(bf16x8*)(wsB + (size_t)idx * 8) = *(bf16x8*)v;
}

__global__ __launch_bounds__(256) void gnn_rnn_kernel(
    const float* __restrict__ x, const float* __restrict__ edge_attr,
    const float* __restrict__ hidden,
    const float* __restrict__ bl, const float* __restrict__ br,
    const float* __restrict__ We, const float* __restrict__ be,
    const float* __restrict__ att, const float* __restrict__ bias_g,
    const float* __restrict__ b_ih, const float* __restrict__ b_hh,
    const float* __restrict__ ln_g, const float* __restrict__ ln_b,
    const float* __restrict__ Wq, const float* __restrict__ bq,
    const u16* __restrict__ wsB,
    float* __restrict__ d_out)
{
  __shared__ __align__(16) u16 s_xb[NAG * ABP];     // x in bf16 (A-frags, phase 2)
  __shared__ __align__(16) u16 s_hidb[NAG * ABP];   // hidden bf16 (A-frags, phase 6)
  __shared__ __align__(16) u16 s_hgb[NAG * ABP];    // h_gnn bf16 (A-frags, phase 6)
  __shared__ __align__(16) float s_hid[NAG][MDIM];  // hidden f32 (gate blend)
  __shared__ float s_ea[EPG * 3];
  __shared__ float s_xl[NAG][HDP];
  __shared__ float s_xr[NAG][HDP];
  __shared__ float s_bl[HD], s_br[HD], s_be[HD], s_att[HD];
  __shared__ float s_We[HD * 3];
  __shared__ float s_bg[DDIM];
  __shared__ float s_alpha[EPG][NHEAD];
  __shared__ float s_gi[NAG][192];
  __shared__ float s_gh[NAG][192];
  __shared__ __align__(16) float s_h[NAG][MDIM];
  __shared__ float s_ln[NAG][65];
  __shared__ float s_Wq[NACT * 65];
  __shared__ float s_bq[NACT];
  __shared__ float s_lng[MDIM], s_lnb[MDIM];
  __shared__ float s_bih[192], s_bhh[192];

  const int t = threadIdx.x;
  const int b = blockIdx.x;
  const int L = t & 63;        // lane
  const int w = t >> 6;        // wave id 0..3
  const int q = L >> 4;        // quad within wave

  // ---------- Phase 1: stage inputs + small weights into LDS ----------
  {
    const float* xb = x + b * (NAG * FIN);
    const float* hb = hidden + b * (NAG * MDIM);
#pragma unroll
    for (int i = t; i < NAG * FIN; i += 256) {
      const int a = i >> 6, m = i & 63;
      s_xb[a * ABP + m] = f2b(xb[i]);
      const float hv = hb[i];
      s_hid[a][m] = hv;
      s_hidb[a * ABP + m] = f2b(hv);
    }
    const float* eb = edge_attr + b * (EPG * 3);
    if (t < EPG * 3) s_ea[t] = eb[t];
    s_bl[t] = bl[t];  s_br[t] = br[t];
    s_be[t] = be[t];  s_att[t] = att[t];
    s_We[t] = We[t]; s_We[t + 256] = We[t + 256]; s_We[t + 512] = We[t + 512];
    if (t < DDIM) { s_bg[t] = bias_g[t]; s_lng[t] = ln_g[t]; s_lnb[t] = ln_b[t]; }
    if (t < 192)  { s_bih[t] = b_ih[t]; s_bhh[t] = b_hh[t]; }
    for (int i = t; i < NACT * MDIM; i += 256) {
      const int o = i >> 6, m = i & 63;
      s_Wq[o * 65 + m] = Wq[i];
    }
    if (t < NACT) s_bq[t] = bq[t];
  }
  __syncthreads();

  // ---------- Phase 2 (MFMA): xl = x@Wl^T+bl, xr = x@Wr^T+br ----------
  // wave w handles 8 of 32 col-tiles (16 cols each): T = 8w..8w+7.
  {
    const int arow = L & 7;
    bf16x8 af0 = *(const bf16x8*)&s_xb[arow * ABP + q * 8];
    bf16x8 af1 = *(const bf16x8*)&s_xb[arow * ABP + 32 + q * 8];
    const bf16x8* wsBv = (const bf16x8*)wsB;
#pragma unroll
    for (int i = 0; i < 8; i++) {
      const int T = w * 8 + i;
      f32x4 acc = {0.f, 0.f, 0.f, 0.f};
      acc = __builtin_amdgcn_mfma_f32_16x16x32_bf16(af0, wsBv[(T * 2 + 0) * 64 + L], acc, 0, 0, 0);
      acc = __builtin_amdgcn_mfma_f32_16x16x32_bf16(af1, wsBv[(T * 2 + 1) * 64 + L], acc, 0, 0, 0);
      if (q < 2) {  // valid rows 0..7 live in quads 0,1 (row = q*4+r)
        const int col = L & 15;
        if (T < 16) {
          const int nb = T * 16;
          const float bias = s_bl[nb + col];
#pragma unroll
          for (int r = 0; r < 4; r++) s_xl[q * 4 + r][nb + col] = acc[r] + bias;
        } else {
          const int nb = (T - 16) * 16;
          const float bias = s_br[nb + col];
#pragma unroll
          for (int r = 0; r < 4; r++) s_xr[q * 4 + r][nb + col] = acc[r] + bias;
        }
      }
    }
  }
  __syncthreads();

  // ---------- Phase 3: edge logits (GATv2). lane map (e,h)=(t%56,t/56): conflict-free-ish ----------
  if (t < EPG * NHEAD) {
    const int e = t % 56, h = t / 56;
    const int s = e / 7, k = e % 7;
    const int j = k + (k >= s ? 1 : 0);   // dst agent
    const float ea0 = s_ea[e * 3], ea1 = s_ea[e * 3 + 1], ea2 = s_ea[e * 3 + 2];
    const float* xls = &s_xl[s][h * 64];
    const float* xrj = &s_xr[j][h * 64];
    const float* wep = &s_We[h * 64 * 3];
    const float* bep = &s_be[h * 64];
    const float* atp = &s_att[h * 64];
    float lg = 0.f;
#pragma unroll 8
    for (int d = 0; d < 64; d++) {
      float ee = ea0 * wep[d * 3] + ea1 * wep[d * 3 + 1] + ea2 * wep[d * 3 + 2] + bep[d];
      float mv = xls[d] + xrj[d] + ee;
      mv = mv > 0.f ? mv : 0.2f * mv;
      lg += mv * atp[d];
    }
    s_alpha[e][h] = lg;
  }
  __syncthreads();

  // ---------- Phase 4: per-(dst,head) softmax over 7 in-edges ----------
  if (t < 32) {
    const int j = t >> 2, h = t & 3;
    float mx = -1e30f;
#pragma unroll
    for (int s = 0; s < 8; s++) {
      if (s == j) continue;
      int e = s * 7 + (j > s ? j - 1 : j);
      mx = fmaxf(mx, s_alpha[e][h]);
    }
    float sum = 0.f;
#pragma unroll
    for (int s = 0; s < 8; s++) {
      if (s == j) continue;
      int e = s * 7 + (j > s ? j - 1 : j);
      float ex = __expf(s_alpha[e][h] - mx);
      s_alpha[e][h] = ex;
      sum += ex;
    }
    float inv = 1.f / sum;
#pragma unroll
    for (int s = 0; s < 8; s++) {
      if (s == j) continue;
      int e = s * 7 + (j > s ? j - 1 : j);
      s_alpha[e][h] *= inv;
    }
  }
  __syncthreads();

  // ---------- Phase 5: aggregate, mean heads, +bias, ReLU -> h_gnn (bf16 A-frags) ----------
  for (int it = t; it < 512; it += 256) {
    const int jj = it >> 6, dd = it & 63;
    float acc = 0.f;
#pragma unroll
    for (int h = 0; h < 4; h++) {
#pragma unroll
      for (int s = 0; s < 8; s++) {
        if (s == jj) continue;
        int e = s * 7 + (jj > s ? jj - 1 : jj);
        acc += s_alpha[e][h] * s_xl[s][h * 64 + dd];
      }
    }
    float v = acc * 0.25f + s_bg[dd];
    s_hgb[jj * ABP + dd] = f2b(v > 0.f ? v : 0.f);
  }
  __syncthreads();

  // ---------- Phase 6 (MFMA): gi = h_gnn@W_ih^T+b_ih, gh = hidden@W_hh^T+b_hh ----------
  // 24 col-tiles total (12 gi + 12 gh); wave w handles T6 = 6w..6w+5.
  // waves 0,1 -> gi (A = s_hgb); waves 2,3 -> gh (A = s_hidb).
  {
    const u16* abase = (w < 2) ? s_hgb : s_hidb;
    const int arow = L & 7;
    bf16x8 af0 = *(const bf16x8*)&abase[arow * ABP + q * 8];
    bf16x8 af1 = *(const bf16x8*)&abase[arow * ABP + 32 + q * 8];
    const bf16x8* wsBv = (const bf16x8*)wsB;
#pragma unroll
    for (int i = 0; i < 6; i++) {
      const int T6 = w * 6 + i;
      const int T = 32 + T6;
      f32x4 acc = {0.f, 0.f, 0.f, 0.f};
      acc = __builtin_amdgcn_mfma_f32_16x16x32_bf16(af0, wsBv[(T * 2 + 0) * 64 + L], acc, 0, 0, 0);
      acc = __builtin_amdgcn_mfma_f32_16x16x32_bf16(af1, wsBv[(T * 2 + 1) * 64 + L], acc, 0, 0, 0);
      if (q < 2) {
        const int col = L & 15;
        if (T6 < 12) {
          const int nb = T6 * 16;
          const float bias = s_bih[nb + col];
#pragma unroll
          for (int r = 0; r < 4; r++) s_gi[q * 4 + r][nb + col] = acc[r] + bias;
        } else {
          const int nb = (T6 - 12) * 16;
          const float bias = s_bhh[nb + col];
#pragma unroll
          for (int r = 0; r < 4; r++) s_gh[q * 4 + r][nb + col] = acc[r] + bias;
        }
      }
    }
  }
  __syncthreads();

  // ---------- Phase 7: GRU gates + write h (output 1, offset N*NACT elems) ----------
  for (int it = t; it < 512; it += 256) {
    const int a = it >> 6, m = it & 63;
    float ir = s_gi[a][m], iz = s_gi[a][64 + m], inn = s_gi[a][128 + m];
    float hr = s_gh[a][m], hz = s_gh[a][64 + m], hn = s_gh[a][128 + m];
    float r = 1.f / (1.f + __expf(-(ir + hr)));
    float z = 1.f / (1.f + __expf(-(iz + hz)));
    float xg = inn + r * hn;
    xg = fminf(fmaxf(xg, -20.f), 20.f);
    float e2 = __expf(2.f * xg);
    float n = (e2 - 1.f) / (e2 + 1.f);
    float hv = (1.f - z) * n + z * s_hid[a][m];
    s_h[a][m] = hv;
    d_out[NTOT * NACT + (b * NAG + a) * MDIM + m] = hv;
  }
  __syncthreads();

  // ---------- Phase 8: LayerNorm (wave w -> rows w and w+4; lane = col) ----------
  {
#pragma unroll
    for (int rr = 0; rr < 2; rr++) {
      const int a = w + rr * 4;
      float v = s_h[a][L];
      float sum = v;
#pragma unroll
      for (int off = 1; off < 64; off <<= 1) sum += __shfl_xor(sum, off, 64);
      float mu = sum * (1.f / 64.f);
      float dv = v - mu;
      float s2 = dv * dv;
#pragma unroll
      for (int off = 1; off < 64; off <<= 1) s2 += __shfl_xor(s2, off, 64);
      float var = s2 * (1.f / 64.f);
      s_ln[a][L] = dv * rsqrtf(var + 1e-5f) * s_lng[L] + s_lnb[L];
    }
  }
  __syncthreads();

  // ---------- Phase 9: q = hln @ Wq^T + bq (output 0) ----------
  if (t < NAG * NACT) {
    const int a = t / NACT, o = t % NACT;
    float acc = s_bq[o];
    const float* lp = s_ln[a];
    const float* wp = &s_Wq[o * 65];
#pragma unroll 8
    for (int m = 0; m < 64; m++) acc += lp[m] * wp[m];
    d_out[(b * NAG + a) * NACT + o] = acc;
  }
}

extern "C" void kernel_launch(void* const* d_in, const int* in_sizes, int n_in,
                              void* d_out, int out_size, void* d_ws, size_t ws_size,
                              hipStream_t stream) {
  const int N  = in_sizes[0] / FIN;   // 32768
  const int Bn = N / NAG;             // 4096 episodes
  u16* wsB = (u16*)d_ws;              // 56*2*64*8 bf16 = 112 KiB

  prep_weights<<<28, 256, 0, stream>>>(
      (const float*)d_in[4],   // Wl
      (const float*)d_in[6],   // Wr
      (const float*)d_in[12],  // W_ih
      (const float*)d_in[13],  // W_hh
      wsB);

  gnn_rnn_kernel<<<Bn, 256, 0, stream>>>(
      (const float*)d_in[0], (const float*)d_in[1], (const float*)d_in[2],
      (const float*)d_in[5],   // bl
      (const float*)d_in[7],   // br
      (const float*)d_in[8],   // We
      (const float*)d_in[9],   // be
      (const float*)d_in[10],  // att
      (const float*)d_in[11],  // bias_g
      (const float*)d_in[14],  // b_ih
      (const float*)d_in[15],  // b_hh
      (const float*)d_in[16], (const float*)d_in[17],  // ln_g, ln_b
      (const float*)d_in[18], (const float*)d_in[19],  // Wq, bq
      wsB, (float*)d_out);
}

// Round 5
// 177.719 us; speedup vs baseline: 7.9206x; 1.1439x over previous
//
#include <hip/hip_runtime.h>

typedef unsigned short u16;
typedef __attribute__((ext_vector_type(8))) short bf16x8;
typedef __attribute__((ext_vector_type(4))) float f32x4;

#define NAG 8      // agents per episode
#define FIN 64
#define MDIM 64
#define NACT 10
#define EPG 56     // edges per group = 8*7
#define NTOT 32768 // B*A
#define ABP 72     // padded bf16 A-row (144 B)
#define XLP 260    // padded f32 xl/xr row (16B-aligned, bank spread 4/row)

// union-region float offsets (region = 16640 B = 4160 floats)
#define OFF_XR 2080          // s_xr after s_xl (8*260)
#define OFF_GI 0             // phase >=6: gi (8*192)
#define OFF_GH 1536          // gh (8*192)
#define OFF_LN 3072          // ln  (8*68)

__device__ __forceinline__ u16 f2b(float f) {
  unsigned int x = __float_as_uint(f);
  unsigned int r = x + 0x7fffu + ((x >> 16) & 1u);   // RNE; values finite
  return (u16)(r >> 16);
}

// ---------- pre-kernel: repack Wl/Wr/W_ih/W_hh into bf16 B-fragment order ----------
__global__ __launch_bounds__(256) void prep_weights(
    const float* __restrict__ Wl, const float* __restrict__ Wr,
    const float* __restrict__ Wih, const float* __restrict__ Whh,
    u16* __restrict__ wsB)
{
  const int idx = blockIdx.x * 256 + threadIdx.x;   // 0 .. 56*2*64-1
  if (idx >= 56 * 2 * 64) return;
  const int L  = idx & 63;
  const int ks = (idx >> 6) & 1;
  const int T  = idx >> 7;
  const float* W; int row0;
  if      (T < 16) { W = Wl;  row0 = T * 16; }
  else if (T < 32) { W = Wr;  row0 = (T - 16) * 16; }
  else if (T < 44) { W = Wih; row0 = (T - 32) * 16; }
  else             { W = Whh; row0 = (T - 44) * 16; }
  const int row = row0 + (L & 15);
  const int k0  = ks * 32 + (L >> 4) * 8;
  u16 v[8];
#pragma unroll
  for (int j = 0; j < 8; j++) v[j] = f2b(W[row * 64 + k0 + j]);
  *(bf16x8*)(wsB + (size_t)idx * 8) = *(bf16x8*)v;
}

__global__ __launch_bounds__(256, 4) void gnn_rnn_kernel(
    const float* __restrict__ x, const float* __restrict__ edge_attr,
    const float* __restrict__ hidden,
    const float* __restrict__ bl, const float* __restrict__ br,
    const float* __restrict__ We, const float* __restrict__ be,
    const float* __restrict__ att, const float* __restrict__ bias_g,
    const float* __restrict__ b_ih, const float* __restrict__ b_hh,
    const float* __restrict__ ln_g, const float* __restrict__ ln_b,
    const float* __restrict__ Wq, const float* __restrict__ bq,
    const u16* __restrict__ wsB,
    float* __restrict__ d_out)
{
  // union region: phases 2-5 hold xl/xr; phases 6-9 hold gi/gh/ln
  __shared__ __align__(16) float uA[4160];
  __shared__ __align__(16) u16 s_xb[NAG * ABP];     // x bf16 A-frags
  __shared__ __align__(16) u16 s_hidb[NAG * ABP];   // hidden bf16 A-frags
  __shared__ __align__(16) u16 s_hgb[NAG * ABP];    // h_gnn bf16 A-frags
  __shared__ __align__(16) float s_hid[NAG][MDIM];  // hidden f32 (gate blend)
  __shared__ float s_ea[EPG * 3];
  __shared__ float s_bl[256], s_br[256];
  __shared__ __align__(16) float s_be[256], s_att[256];
  __shared__ __align__(16) float s_w0[256], s_w1[256], s_w2[256];
  __shared__ float s_bg[MDIM];
  __shared__ float s_alpha[EPG][4];
  __shared__ float s_bq[NACT];
  __shared__ float s_lng[MDIM], s_lnb[MDIM];
  __shared__ float s_bih[192], s_bhh[192];

  const int t = threadIdx.x;
  const int b = blockIdx.x;
  const int L = t & 63;        // lane
  const int w = t >> 6;        // wave id 0..3
  const int q = L >> 4;        // quad within wave

  // ---------- Phase 1: stage inputs + small weights ----------
  {
    const float* xb = x + b * (NAG * FIN);
    const float* hb = hidden + b * (NAG * MDIM);
#pragma unroll
    for (int i = t; i < NAG * FIN; i += 256) {
      const int a = i >> 6, m = i & 63;
      s_xb[a * ABP + m] = f2b(xb[i]);
      const float hv = hb[i];
      s_hid[a][m] = hv;
      s_hidb[a * ABP + m] = f2b(hv);
    }
    const float* eb = edge_attr + b * (EPG * 3);
    if (t < EPG * 3) s_ea[t] = eb[t];
    s_bl[t] = bl[t];  s_br[t] = br[t];
    s_be[t] = be[t];  s_att[t] = att[t];
    s_w0[t] = We[t * 3]; s_w1[t] = We[t * 3 + 1]; s_w2[t] = We[t * 3 + 2];
    if (t < MDIM) { s_bg[t] = bias_g[t]; s_lng[t] = ln_g[t]; s_lnb[t] = ln_b[t]; }
    if (t < 192)  { s_bih[t] = b_ih[t]; s_bhh[t] = b_hh[t]; }
    if (t < NACT) s_bq[t] = bq[t];
  }
  __syncthreads();

  // ---------- Phase 2 (MFMA): xl = x@Wl^T+bl, xr = x@Wr^T+br ----------
  {
    const int arow = L & 7;
    bf16x8 af0 = *(const bf16x8*)&s_xb[arow * ABP + q * 8];
    bf16x8 af1 = *(const bf16x8*)&s_xb[arow * ABP + 32 + q * 8];
    const bf16x8* wsBv = (const bf16x8*)wsB;
#pragma unroll
    for (int i = 0; i < 8; i++) {
      const int T = w * 8 + i;
      f32x4 acc = {0.f, 0.f, 0.f, 0.f};
      acc = __builtin_amdgcn_mfma_f32_16x16x32_bf16(af0, wsBv[(T * 2 + 0) * 64 + L], acc, 0, 0, 0);
      acc = __builtin_amdgcn_mfma_f32_16x16x32_bf16(af1, wsBv[(T * 2 + 1) * 64 + L], acc, 0, 0, 0);
      if (q < 2) {  // valid rows 0..7 in quads 0,1 (row = q*4+r)
        const int col = L & 15;
        if (T < 16) {
          const int nb = T * 16;
          const float bias = s_bl[nb + col];
#pragma unroll
          for (int r = 0; r < 4; r++) uA[(q * 4 + r) * XLP + nb + col] = acc[r] + bias;
        } else {
          const int nb = (T - 16) * 16;
          const float bias = s_br[nb + col];
#pragma unroll
          for (int r = 0; r < 4; r++) uA[OFF_XR + (q * 4 + r) * XLP + nb + col] = acc[r] + bias;
        }
      }
    }
  }
  __syncthreads();

  // ---------- Phase 3: edge logits (GATv2), float4 LDS reads ----------
  if (t < EPG * 4) {
    const int e = t % 56, h = t / 56;
    const int s = e / 7, k = e % 7;
    const int j = k + (k >= s ? 1 : 0);   // dst agent
    const float ea0 = s_ea[e * 3], ea1 = s_ea[e * 3 + 1], ea2 = s_ea[e * 3 + 2];
    const float4* xlv = (const float4*)(uA + s * XLP + h * 64);
    const float4* xrv = (const float4*)(uA + OFF_XR + j * XLP + h * 64);
    const float4* w0v = (const float4*)(s_w0 + h * 64);
    const float4* w1v = (const float4*)(s_w1 + h * 64);
    const float4* w2v = (const float4*)(s_w2 + h * 64);
    const float4* bev = (const float4*)(s_be + h * 64);
    const float4* atv = (const float4*)(s_att + h * 64);
    float lg = 0.f;
#pragma unroll 4
    for (int kq = 0; kq < 16; kq++) {
      float4 xa = xlv[kq], xbv = xrv[kq];
      float4 a0 = w0v[kq], a1 = w1v[kq], a2 = w2v[kq];
      float4 bb = bev[kq], at = atv[kq];
      float p0 = xa.x + xbv.x + ea0 * a0.x + ea1 * a1.x + ea2 * a2.x + bb.x;
      float p1 = xa.y + xbv.y + ea0 * a0.y + ea1 * a1.y + ea2 * a2.y + bb.y;
      float p2 = xa.z + xbv.z + ea0 * a0.z + ea1 * a1.z + ea2 * a2.z + bb.z;
      float p3 = xa.w + xbv.w + ea0 * a0.w + ea1 * a1.w + ea2 * a2.w + bb.w;
      p0 = p0 > 0.f ? p0 : 0.2f * p0;
      p1 = p1 > 0.f ? p1 : 0.2f * p1;
      p2 = p2 > 0.f ? p2 : 0.2f * p2;
      p3 = p3 > 0.f ? p3 : 0.2f * p3;
      lg += p0 * at.x + p1 * at.y + p2 * at.z + p3 * at.w;
    }
    s_alpha[e][h] = lg;
  }
  __syncthreads();

  // ---------- Phase 4: per-(dst,head) softmax over 7 in-edges ----------
  if (t < 32) {
    const int j = t >> 2, h = t & 3;
    float mx = -1e30f;
#pragma unroll
    for (int s = 0; s < 8; s++) {
      if (s == j) continue;
      int e = s * 7 + (j > s ? j - 1 : j);
      mx = fmaxf(mx, s_alpha[e][h]);
    }
    float sum = 0.f;
#pragma unroll
    for (int s = 0; s < 8; s++) {
      if (s == j) continue;
      int e = s * 7 + (j > s ? j - 1 : j);
      float ex = __expf(s_alpha[e][h] - mx);
      s_alpha[e][h] = ex;
      sum += ex;
    }
    float inv = 1.f / sum;
#pragma unroll
    for (int s = 0; s < 8; s++) {
      if (s == j) continue;
      int e = s * 7 + (j > s ? j - 1 : j);
      s_alpha[e][h] *= inv;
    }
  }
  __syncthreads();

  // ---------- Phase 5: aggregate, mean heads, +bias, ReLU -> h_gnn bf16 ----------
  for (int it = t; it < 512; it += 256) {
    const int jj = it >> 6, dd = it & 63;
    float acc = 0.f;
#pragma unroll
    for (int h = 0; h < 4; h++) {
#pragma unroll
      for (int s = 0; s < 8; s++) {
        if (s == jj) continue;
        int e = s * 7 + (jj > s ? jj - 1 : jj);
        acc += s_alpha[e][h] * uA[s * XLP + h * 64 + dd];
      }
    }
    float v = acc * 0.25f + s_bg[dd];
    s_hgb[jj * ABP + dd] = f2b(v > 0.f ? v : 0.f);
  }
  __syncthreads();   // after this barrier uA region becomes gi/gh/ln

  // ---------- Phase 6 (MFMA): gi = h_gnn@W_ih^T+b_ih, gh = hidden@W_hh^T+b_hh ----------
  {
    const u16* abase = (w < 2) ? s_hgb : s_hidb;
    const int arow = L & 7;
    bf16x8 af0 = *(const bf16x8*)&abase[arow * ABP + q * 8];
    bf16x8 af1 = *(const bf16x8*)&abase[arow * ABP + 32 + q * 8];
    const bf16x8* wsBv = (const bf16x8*)wsB;
#pragma unroll
    for (int i = 0; i < 6; i++) {
      const int T6 = w * 6 + i;
      const int T = 32 + T6;
      f32x4 acc = {0.f, 0.f, 0.f, 0.f};
      acc = __builtin_amdgcn_mfma_f32_16x16x32_bf16(af0, wsBv[(T * 2 + 0) * 64 + L], acc, 0, 0, 0);
      acc = __builtin_amdgcn_mfma_f32_16x16x32_bf16(af1, wsBv[(T * 2 + 1) * 64 + L], acc, 0, 0, 0);
      if (q < 2) {
        const int col = L & 15;
        if (T6 < 12) {
          const int nb = T6 * 16;
          const float bias = s_bih[nb + col];
#pragma unroll
          for (int r = 0; r < 4; r++) uA[OFF_GI + (q * 4 + r) * 192 + nb + col] = acc[r] + bias;
        } else {
          const int nb = (T6 - 12) * 16;
          const float bias = s_bhh[nb + col];
#pragma unroll
          for (int r = 0; r < 4; r++) uA[OFF_GH + (q * 4 + r) * 192 + nb + col] = acc[r] + bias;
        }
      }
    }
  }
  __syncthreads();

  // ---------- Phase 7+8 merged: GRU gates, write h, in-wave LayerNorm ----------
#pragma unroll
  for (int rr = 0; rr < 2; rr++) {
    const int a = w + rr * 4, m = L;
    float ir = uA[OFF_GI + a * 192 + m], iz = uA[OFF_GI + a * 192 + 64 + m],
          inn = uA[OFF_GI + a * 192 + 128 + m];
    float hr = uA[OFF_GH + a * 192 + m], hz = uA[OFF_GH + a * 192 + 64 + m],
          hn = uA[OFF_GH + a * 192 + 128 + m];
    float r = 1.f / (1.f + __expf(-(ir + hr)));
    float z = 1.f / (1.f + __expf(-(iz + hz)));
    float xg = inn + r * hn;
    xg = fminf(fmaxf(xg, -20.f), 20.f);
    float e2 = __expf(2.f * xg);
    float n = (e2 - 1.f) / (e2 + 1.f);
    float hv = (1.f - z) * n + z * s_hid[a][m];
    d_out[NTOT * NACT + (b * NAG + a) * MDIM + m] = hv;
    // LayerNorm across the wave (lane = feature)
    float sum = hv;
#pragma unroll
    for (int off = 1; off < 64; off <<= 1) sum += __shfl_xor(sum, off, 64);
    float mu = sum * (1.f / 64.f);
    float dv = hv - mu;
    float s2 = dv * dv;
#pragma unroll
    for (int off = 1; off < 64; off <<= 1) s2 += __shfl_xor(s2, off, 64);
    float var = s2 * (1.f / 64.f);
    uA[OFF_LN + a * 68 + m] = dv * rsqrtf(var + 1e-5f) * s_lng[m] + s_lnb[m];
  }
  __syncthreads();

  // ---------- Phase 9: q = hln @ Wq^T + bq (Wq from global, L2-hot) ----------
  if (t < NAG * NACT) {
    const int a = t / NACT, o = t % NACT;
    float acc = s_bq[o];
    const float4* lv = (const float4*)(uA + OFF_LN + a * 68);
    const float4* wv = (const float4*)(Wq + o * 64);
#pragma unroll 4
    for (int kq = 0; kq < 16; kq++) {
      float4 l4 = lv[kq], w4 = wv[kq];
      acc += l4.x * w4.x + l4.y * w4.y + l4.z * w4.z + l4.w * w4.w;
    }
    d_out[(b * NAG + a) * NACT + o] = acc;
  }
}

extern "C" void kernel_launch(void* const* d_in, const int* in_sizes, int n_in,
                              void* d_out, int out_size, void* d_ws, size_t ws_size,
                              hipStream_t stream) {
  const int N  = in_sizes[0] / FIN;   // 32768
  const int Bn = N / NAG;             // 4096 episodes
  u16* wsB = (u16*)d_ws;              // 56*2*64*8 bf16 = 112 KiB

  prep_weights<<<28, 256, 0, stream>>>(
      (const float*)d_in[4],   // Wl
      (const float*)d_in[6],   // Wr
      (const float*)d_in[12],  // W_ih
      (const float*)d_in[13],  // W_hh
      wsB);

  gnn_rnn_kernel<<<Bn, 256, 0, stream>>>(
      (const float*)d_in[0], (const float*)d_in[1], (const float*)d_in[2],
      (const float*)d_in[5],   // bl
      (const float*)d_in[7],   // br
      (const float*)d_in[8],   // We
      (const float*)d_in[9],   // be
      (const float*)d_in[10],  // att
      (const float*)d_in[11],  // bias_g
      (const float*)d_in[14],  // b_ih
      (const float*)d_in[15],  // b_hh
      (const float*)d_in[16], (const float*)d_in[17],  // ln_g, ln_b
      (const float*)d_in[18], (const float*)d_in[19],  // Wq, bq
      wsB, (float*)d_out);
}

// Round 6
// 172.412 us; speedup vs baseline: 8.1644x; 1.0308x over previous
//
#include <hip/hip_runtime.h>

typedef unsigned short u16;
typedef __attribute__((ext_vector_type(8))) short bf16x8;
typedef __attribute__((ext_vector_type(4))) float f32x4;

#define NAG 8      // agents per episode
#define FIN 64
#define MDIM 64
#define NACT 10
#define EPG 56     // edges per group = 8*7
#define NTOT 32768 // B*A
#define ABP 72     // padded bf16 A-row (144 B)
#define XLP 260    // padded f32 xl/xr row (16B-aligned, bank spread 4/row)

// union-region float offsets (region = 16640 B = 4160 floats)
#define OFF_XR 2080          // s_xr after s_xl (8*260)
#define OFF_GI 0             // phase >=6: gi (8*192)
#define OFF_GH 1536          // gh (8*192)
#define OFF_LN 3072          // ln  (8*68)

__device__ __forceinline__ u16 f2b(float f) {
  unsigned int x = __float_as_uint(f);
  unsigned int r = x + 0x7fffu + ((x >> 16) & 1u);   // RNE; values finite
  return (u16)(r >> 16);
}

// ---------- pre-kernel: repack Wl/Wr/W_ih/W_hh into bf16 B-fragment order ----------
__global__ __launch_bounds__(256) void prep_weights(
    const float* __restrict__ Wl, const float* __restrict__ Wr,
    const float* __restrict__ Wih, const float* __restrict__ Whh,
    u16* __restrict__ wsB)
{
  const int idx = blockIdx.x * 256 + threadIdx.x;   // 0 .. 56*2*64-1
  if (idx >= 56 * 2 * 64) return;
  const int L  = idx & 63;
  const int ks = (idx >> 6) & 1;
  const int T  = idx >> 7;
  const float* W; int row0;
  if      (T < 16) { W = Wl;  row0 = T * 16; }
  else if (T < 32) { W = Wr;  row0 = (T - 16) * 16; }
  else if (T < 44) { W = Wih; row0 = (T - 32) * 16; }
  else             { W = Whh; row0 = (T - 44) * 16; }
  const int row = row0 + (L & 15);
  const int k0  = ks * 32 + (L >> 4) * 8;
  u16 v[8];
#pragma unroll
  for (int j = 0; j < 8; j++) v[j] = f2b(W[row * 64 + k0 + j]);
  *(bf16x8*)(wsB + (size_t)idx * 8) = *(bf16x8*)v;
}

__global__ __launch_bounds__(256, 5) void gnn_rnn_kernel(
    const float* __restrict__ x, const float* __restrict__ edge_attr,
    const float* __restrict__ hidden,
    const float* __restrict__ bl, const float* __restrict__ br,
    const float* __restrict__ We, const float* __restrict__ be,
    const float* __restrict__ att, const float* __restrict__ bias_g,
    const float* __restrict__ b_ih, const float* __restrict__ b_hh,
    const float* __restrict__ ln_g, const float* __restrict__ ln_b,
    const float* __restrict__ Wq, const float* __restrict__ bq,
    const u16* __restrict__ wsB,
    float* __restrict__ d_out)
{
  // union region: phases 2-5 hold xl/xr; phases 6-9 hold gi/gh/ln
  __shared__ __align__(16) float uA[4160];
  __shared__ __align__(16) u16 s_xb[NAG * ABP];     // x bf16 A-frags
  __shared__ __align__(16) u16 s_hidb[NAG * ABP];   // hidden bf16 A-frags
  __shared__ __align__(16) u16 s_hgb[NAG * ABP];    // h_gnn bf16 A-frags
  __shared__ __align__(16) float s_hid[NAG][MDIM];  // hidden f32 (gate blend)
  __shared__ float s_ea[EPG * 3];
  __shared__ float s_bl[256], s_br[256];
  __shared__ __align__(16) float s_be[256], s_att[256];
  __shared__ __align__(16) float s_w0[256], s_w1[256], s_w2[256];
  __shared__ float s_alpha[EPG][4];
  __shared__ float s_bih[192], s_bhh[192];

  const int t = threadIdx.x;
  const int b = blockIdx.x;
  const int L = t & 63;        // lane
  const int w = t >> 6;        // wave id 0..3
  const int q = L >> 4;        // quad within wave

  // ---------- Phase 1: stage inputs + small weights ----------
  {
    const float* xb = x + b * (NAG * FIN);
    const float* hb = hidden + b * (NAG * MDIM);
#pragma unroll
    for (int i = t; i < NAG * FIN; i += 256) {
      const int a = i >> 6, m = i & 63;
      s_xb[a * ABP + m] = f2b(xb[i]);
      const float hv = hb[i];
      s_hid[a][m] = hv;
      s_hidb[a * ABP + m] = f2b(hv);
    }
    const float* eb = edge_attr + b * (EPG * 3);
    if (t < EPG * 3) s_ea[t] = eb[t];
    s_bl[t] = bl[t];  s_br[t] = br[t];
    s_be[t] = be[t];  s_att[t] = att[t];
    s_w0[t] = We[t * 3]; s_w1[t] = We[t * 3 + 1]; s_w2[t] = We[t * 3 + 2];
    if (t < 192)  { s_bih[t] = b_ih[t]; s_bhh[t] = b_hh[t]; }
  }
  __syncthreads();

  // ---------- Phase 2 (MFMA): xl = x@Wl^T+bl, xr = x@Wr^T+br ----------
  {
    const int arow = L & 7;
    bf16x8 af0 = *(const bf16x8*)&s_xb[arow * ABP + q * 8];
    bf16x8 af1 = *(const bf16x8*)&s_xb[arow * ABP + 32 + q * 8];
    const bf16x8* wsBv = (const bf16x8*)wsB;
#pragma unroll
    for (int i = 0; i < 8; i++) {
      const int T = w * 8 + i;
      f32x4 acc = {0.f, 0.f, 0.f, 0.f};
      acc = __builtin_amdgcn_mfma_f32_16x16x32_bf16(af0, wsBv[(T * 2 + 0) * 64 + L], acc, 0, 0, 0);
      acc = __builtin_amdgcn_mfma_f32_16x16x32_bf16(af1, wsBv[(T * 2 + 1) * 64 + L], acc, 0, 0, 0);
      if (q < 2) {  // valid rows 0..7 in quads 0,1 (row = q*4+r)
        const int col = L & 15;
        if (T < 16) {
          const int nb = T * 16;
          const float bias = s_bl[nb + col];
#pragma unroll
          for (int r = 0; r < 4; r++) uA[(q * 4 + r) * XLP + nb + col] = acc[r] + bias;
        } else {
          const int nb = (T - 16) * 16;
          const float bias = s_br[nb + col];
#pragma unroll
          for (int r = 0; r < 4; r++) uA[OFF_XR + (q * 4 + r) * XLP + nb + col] = acc[r] + bias;
        }
      }
    }
  }
  __syncthreads();

  // ---------- Phase 3: edge logits (GATv2), float4 LDS reads ----------
  if (t < EPG * 4) {
    const int e = t % 56, h = t / 56;
    const int s = e / 7, k = e % 7;
    const int j = k + (k >= s ? 1 : 0);   // dst agent
    const float ea0 = s_ea[e * 3], ea1 = s_ea[e * 3 + 1], ea2 = s_ea[e * 3 + 2];
    const float4* xlv = (const float4*)(uA + s * XLP + h * 64);
    const float4* xrv = (const float4*)(uA + OFF_XR + j * XLP + h * 64);
    const float4* w0v = (const float4*)(s_w0 + h * 64);
    const float4* w1v = (const float4*)(s_w1 + h * 64);
    const float4* w2v = (const float4*)(s_w2 + h * 64);
    const float4* bev = (const float4*)(s_be + h * 64);
    const float4* atv = (const float4*)(s_att + h * 64);
    float lg = 0.f;
#pragma unroll 4
    for (int kq = 0; kq < 16; kq++) {
      float4 xa = xlv[kq], xbv = xrv[kq];
      float4 a0 = w0v[kq], a1 = w1v[kq], a2 = w2v[kq];
      float4 bb = bev[kq], at = atv[kq];
      float p0 = xa.x + xbv.x + ea0 * a0.x + ea1 * a1.x + ea2 * a2.x + bb.x;
      float p1 = xa.y + xbv.y + ea0 * a0.y + ea1 * a1.y + ea2 * a2.y + bb.y;
      float p2 = xa.z + xbv.z + ea0 * a0.z + ea1 * a1.z + ea2 * a2.z + bb.z;
      float p3 = xa.w + xbv.w + ea0 * a0.w + ea1 * a1.w + ea2 * a2.w + bb.w;
      p0 = p0 > 0.f ? p0 : 0.2f * p0;
      p1 = p1 > 0.f ? p1 : 0.2f * p1;
      p2 = p2 > 0.f ? p2 : 0.2f * p2;
      p3 = p3 > 0.f ? p3 : 0.2f * p3;
      lg += p0 * at.x + p1 * at.y + p2 * at.z + p3 * at.w;
    }
    s_alpha[e][h] = lg;
  }
  __syncthreads();

  // ---------- Phase 4: per-(dst,head) softmax over 7 in-edges ----------
  if (t < 32) {
    const int j = t >> 2, h = t & 3;
    float mx = -1e30f;
#pragma unroll
    for (int s = 0; s < 8; s++) {
      if (s == j) continue;
      int e = s * 7 + (j > s ? j - 1 : j);
      mx = fmaxf(mx, s_alpha[e][h]);
    }
    float sum = 0.f;
#pragma unroll
    for (int s = 0; s < 8; s++) {
      if (s == j) continue;
      int e = s * 7 + (j > s ? j - 1 : j);
      float ex = __expf(s_alpha[e][h] - mx);
      s_alpha[e][h] = ex;
      sum += ex;
    }
    float inv = 1.f / sum;
#pragma unroll
    for (int s = 0; s < 8; s++) {
      if (s == j) continue;
      int e = s * 7 + (j > s ? j - 1 : j);
      s_alpha[e][h] *= inv;
    }
  }
  __syncthreads();

  // ---------- Phase 5: aggregate (float4), mean heads, +bias, ReLU -> h_gnn bf16 ----------
  if (t < 128) {
    const int jj = t >> 4, dq = t & 15;   // dst agent, d-quad (4 floats)
    f32x4 acc = {0.f, 0.f, 0.f, 0.f};
#pragma unroll
    for (int h = 0; h < 4; h++) {
#pragma unroll
      for (int s = 0; s < 8; s++) {
        if (s == jj) continue;
        int e = s * 7 + (jj > s ? jj - 1 : jj);
        float al = s_alpha[e][h];              // broadcast across 16 lanes
        const f32x4 xv = *(const f32x4*)(uA + s * XLP + h * 64 + dq * 4);
        acc += al * xv;
      }
    }
    const f32x4 bg = *(const f32x4*)(bias_g + dq * 4);   // global, L2-hot
    u16 pk[4];
#pragma unroll
    for (int c = 0; c < 4; c++) {
      float v = acc[c] * 0.25f + bg[c];
      pk[c] = f2b(v > 0.f ? v : 0.f);
    }
    *(uint2*)&s_hgb[jj * ABP + dq * 4] = *(uint2*)pk;
  }
  __syncthreads();   // after this barrier uA region becomes gi/gh/ln

  // ---------- Phase 6 (MFMA): gi = h_gnn@W_ih^T+b_ih, gh = hidden@W_hh^T+b_hh ----------
  {
    const u16* abase = (w < 2) ? s_hgb : s_hidb;
    const int arow = L & 7;
    bf16x8 af0 = *(const bf16x8*)&abase[arow * ABP + q * 8];
    bf16x8 af1 = *(const bf16x8*)&abase[arow * ABP + 32 + q * 8];
    const bf16x8* wsBv = (const bf16x8*)wsB;
#pragma unroll
    for (int i = 0; i < 6; i++) {
      const int T6 = w * 6 + i;
      const int T = 32 + T6;
      f32x4 acc = {0.f, 0.f, 0.f, 0.f};
      acc = __builtin_amdgcn_mfma_f32_16x16x32_bf16(af0, wsBv[(T * 2 + 0) * 64 + L], acc, 0, 0, 0);
      acc = __builtin_amdgcn_mfma_f32_16x16x32_bf16(af1, wsBv[(T * 2 + 1) * 64 + L], acc, 0, 0, 0);
      if (q < 2) {
        const int col = L & 15;
        if (T6 < 12) {
          const int nb = T6 * 16;
          const float bias = s_bih[nb + col];
#pragma unroll
          for (int r = 0; r < 4; r++) uA[OFF_GI + (q * 4 + r) * 192 + nb + col] = acc[r] + bias;
        } else {
          const int nb = (T6 - 12) * 16;
          const float bias = s_bhh[nb + col];
#pragma unroll
          for (int r = 0; r < 4; r++) uA[OFF_GH + (q * 4 + r) * 192 + nb + col] = acc[r] + bias;
        }
      }
    }
  }
  __syncthreads();

  // ---------- Phase 7+8 merged: GRU gates, write h, in-wave LayerNorm ----------
  {
    const float lng = ln_g[L];   // global, L2-hot
    const float lnb = ln_b[L];
#pragma unroll
    for (int rr = 0; rr < 2; rr++) {
      const int a = w + rr * 4, m = L;
      float ir = uA[OFF_GI + a * 192 + m], iz = uA[OFF_GI + a * 192 + 64 + m],
            inn = uA[OFF_GI + a * 192 + 128 + m];
      float hr = uA[OFF_GH + a * 192 + m], hz = uA[OFF_GH + a * 192 + 64 + m],
            hn = uA[OFF_GH + a * 192 + 128 + m];
      float r = 1.f / (1.f + __expf(-(ir + hr)));
      float z = 1.f / (1.f + __expf(-(iz + hz)));
      float xg = inn + r * hn;
      xg = fminf(fmaxf(xg, -20.f), 20.f);
      float e2 = __expf(2.f * xg);
      float n = (e2 - 1.f) / (e2 + 1.f);
      float hv = (1.f - z) * n + z * s_hid[a][m];
      d_out[NTOT * NACT + (b * NAG + a) * MDIM + m] = hv;
      // LayerNorm across the wave (lane = feature)
      float sum = hv;
#pragma unroll
      for (int off = 1; off < 64; off <<= 1) sum += __shfl_xor(sum, off, 64);
      float mu = sum * (1.f / 64.f);
      float dv = hv - mu;
      float s2 = dv * dv;
#pragma unroll
      for (int off = 1; off < 64; off <<= 1) s2 += __shfl_xor(s2, off, 64);
      float var = s2 * (1.f / 64.f);
      uA[OFF_LN + a * 68 + m] = dv * rsqrtf(var + 1e-5f) * lng + lnb;
    }
  }
  __syncthreads();

  // ---------- Phase 9: q = hln @ Wq^T + bq (Wq/bq from global, L2-hot) ----------
  if (t < NAG * NACT) {
    const int a = t / NACT, o = t % NACT;
    float acc = bq[o];
    const float4* lv = (const float4*)(uA + OFF_LN + a * 68);
    const float4* wv = (const float4*)(Wq + o * 64);
#pragma unroll 4
    for (int kq = 0; kq < 16; kq++) {
      float4 l4 = lv[kq], w4 = wv[kq];
      acc += l4.x * w4.x + l4.y * w4.y + l4.z * w4.z + l4.w * w4.w;
    }
    d_out[(b * NAG + a) * NACT + o] = acc;
  }
}

extern "C" void kernel_launch(void* const* d_in, const int* in_sizes, int n_in,
                              void* d_out, int out_size, void* d_ws, size_t ws_size,
                              hipStream_t stream) {
  const int N  = in_sizes[0] / FIN;   // 32768
  const int Bn = N / NAG;             // 4096 episodes
  u16* wsB = (u16*)d_ws;              // 56*2*64*8 bf16 = 112 KiB

  prep_weights<<<28, 256, 0, stream>>>(
      (const float*)d_in[4],   // Wl
      (const float*)d_in[6],   // Wr
      (const float*)d_in[12],  // W_ih
      (const float*)d_in[13],  // W_hh
      wsB);

  gnn_rnn_kernel<<<Bn, 256, 0, stream>>>(
      (const float*)d_in[0], (const float*)d_in[1], (const float*)d_in[2],
      (const float*)d_in[5],   // bl
      (const float*)d_in[7],   // br
      (const float*)d_in[8],   // We
      (const float*)d_in[9],   // be
      (const float*)d_in[10],  // att
      (const float*)d_in[11],  // bias_g
      (const float*)d_in[14],  // b_ih
      (const float*)d_in[15],  // b_hh
      (const float*)d_in[16], (const float*)d_in[17],  // ln_g, ln_b
      (const float*)d_in[18], (const float*)d_in[19],  // Wq, bq
      wsB, (float*)d_out);
}